// Round 19
// baseline (724.938 us; speedup 1.0000x reference)
//
#include <hip/hip_runtime.h>
#include <hip/hip_bf16.h>

#define N_NODES 50000
#define N_EDGES 800000
#define DIM 128
#define NLAYERS 3

typedef short bf16x8 __attribute__((ext_vector_type(8)));
typedef float floatx4 __attribute__((ext_vector_type(4)));
typedef float floatx2 __attribute__((ext_vector_type(2)));

__device__ __forceinline__ unsigned short f2bf(float f) {
  unsigned int u = __builtin_bit_cast(unsigned int, f);
  return (unsigned short)((u + 0x7FFFu + ((u >> 16) & 1u)) >> 16);
}
__device__ __forceinline__ float bf2f(unsigned short h) {
  return __builtin_bit_cast(float, (unsigned int)h << 16);
}

// ---------------- embedding gather -> bf16 residual ----------------
__global__ __launch_bounds__(256) void embed_kernel(
    const int* __restrict__ idx, const float* __restrict__ emb,
    unsigned short* __restrict__ xb)
{
  int gid = blockIdx.x * 256 + threadIdx.x;
  int n = gid >> 5;
  int c = (gid & 31) << 2;
  if (n >= N_NODES) return;
  int e = idx[n];
  float4 val = *(const float4*)(emb + (size_t)e * DIM + c);
  ushort4 pk;
  pk.x = f2bf(val.x); pk.y = f2bf(val.y); pk.z = f2bf(val.z); pk.w = f2bf(val.w);
  *(ushort4*)(xb + (size_t)n * DIM + c) = pk;
}

// ---------------- CSR build ----------------
__global__ __launch_bounds__(256) void hist_kernel(
    const int* __restrict__ e1, int* __restrict__ counts,
    int* __restrict__ rank)
{
  int i = blockIdx.x * 256 + threadIdx.x;
  if (i < N_EDGES) rank[i] = atomicAdd(&counts[e1[i]], 1);
}

__global__ __launch_bounds__(256) void scan_local(
    const int* __restrict__ counts, int* __restrict__ offsets,
    int* __restrict__ bsums)
{
  __shared__ int buf[256];
  int t = threadIdx.x;
  int i = blockIdx.x * 256 + t;
  int v = (i < N_NODES) ? counts[i] : 0;
  buf[t] = v;
  __syncthreads();
  int s = v;
#pragma unroll
  for (int off = 1; off < 256; off <<= 1) {
    int t2 = (t >= off) ? buf[t - off] : 0;
    __syncthreads();
    s += t2;
    buf[t] = s;
    __syncthreads();
  }
  if (i < N_NODES) offsets[i] = s - v;
  if (t == 255) bsums[blockIdx.x] = s;
}

__global__ void scan_bsums(int* __restrict__ bsums, int nblk)
{
  __shared__ int buf[256];
  int t = threadIdx.x;
  int v = (t < nblk) ? bsums[t] : 0;
  buf[t] = v;
  __syncthreads();
  int s = v;
#pragma unroll
  for (int off = 1; off < 256; off <<= 1) {
    int t2 = (t >= off) ? buf[t - off] : 0;
    __syncthreads();
    s += t2;
    buf[t] = s;
    __syncthreads();
  }
  if (t < nblk) bsums[t] = s - v;
}

__global__ __launch_bounds__(256) void scan_add(
    int* __restrict__ offsets, const int* __restrict__ bsums)
{
  int i = blockIdx.x * 256 + threadIdx.x;
  if (i < N_NODES) offsets[i] += bsums[blockIdx.x];
  if (i == 0) offsets[N_NODES] = N_EDGES;
}

__global__ __launch_bounds__(256) void scatter_kernel(
    const int* __restrict__ e0, const int* __restrict__ e1,
    const int* __restrict__ offsets, const int* __restrict__ rank,
    int* __restrict__ csr)
{
  int i = blockIdx.x * 256 + threadIdx.x;
  if (i >= N_EDGES) return;
  csr[offsets[e1[i]] + rank[i]] = e0[i];
}

// ---------------- combined weight prep (single-plane bf16, frag-major) ----------------
__global__ __launch_bounds__(256) void prep_all(
    const float* __restrict__ Wq, const float* __restrict__ Wk,
    const float* __restrict__ Wv, const float* __restrict__ Wo,
    const float* __restrict__ Wf1, const float* __restrict__ Wf2,
    unsigned short* __restrict__ wqkv, unsigned short* __restrict__ wo,
    unsigned short* __restrict__ wf1, unsigned short* __restrict__ wf2)
{
  int g = blockIdx.x * 256 + threadIdx.x;
  if (g < 18432) {
    int srcId = g / 6144; int rem = g - srcId * 6144;
    const float* W = (srcId == 0) ? Wq : (srcId == 1) ? Wk : Wv;
    int l = rem / 2048; int r2 = rem & 2047; int kq = r2 >> 7; int n = r2 & 127;
    const float* Wl = W + (size_t)l * 128 * 128;
    unsigned short* base = wqkv + (size_t)l * 128 * 384 + (size_t)(kq * 384 + srcId * 128 + n) * 8;
#pragma unroll
    for (int j = 0; j < 8; j++)
      base[j] = f2bf(Wl[(size_t)(kq * 8 + j) * 128 + n]);
    return;
  }
  g -= 18432;
  if (g < 6144) {
    int l = g / 2048; int r2 = g & 2047; int kq = r2 >> 7; int n = r2 & 127;
    const float* Wl = Wo + (size_t)l * 128 * 128;
    unsigned short* base = wo + (size_t)l * 128 * 128 + (size_t)(kq * 128 + n) * 8;
#pragma unroll
    for (int j = 0; j < 8; j++)
      base[j] = f2bf(Wl[(size_t)(kq * 8 + j) * 128 + n]);
    return;
  }
  g -= 6144;
  if (g < 12288) {
    int l = g / 4096; int r2 = g & 4095; int kq = r2 >> 8; int n = r2 & 255;
    const float* Wl = Wf1 + (size_t)l * 128 * 256;
    unsigned short* base = wf1 + (size_t)l * 128 * 256 + (size_t)(kq * 256 + n) * 8;
#pragma unroll
    for (int j = 0; j < 8; j++)
      base[j] = f2bf(Wl[(size_t)(kq * 8 + j) * 256 + n]);
    return;
  }
  g -= 12288;
  if (g < 12288) {
    int l = g / 4096; int r2 = g & 4095; int kq = r2 >> 7; int n = r2 & 127;
    const float* Wl = Wf2 + (size_t)l * 256 * 128;
    unsigned short* base = wf2 + (size_t)l * 256 * 128 + (size_t)(kq * 128 + n) * 8;
#pragma unroll
    for (int j = 0; j < 8; j++)
      base[j] = f2bf(Wl[(size_t)(kq * 8 + j) * 128 + n]);
  }
}

#define LSTR 136

// ---------------- layer-0 QKV (LDS-staged vector stores) ----------------
__global__ __launch_bounds__(256) void qkv0_kernel(
    const unsigned short* __restrict__ xb,
    const unsigned short* __restrict__ wqkv,
    const float* __restrict__ bq, const float* __restrict__ bk,
    const float* __restrict__ bv,
    unsigned short* __restrict__ qkv, int nrows)
{
  __shared__ unsigned short XR[64 * LSTR];
  int tid = threadIdx.x;
  int wave = tid >> 6, lane = tid & 63;
  int quad = lane >> 4, l16 = lane & 15;
  int rbase = blockIdx.x * 64;
  int wrow = wave * 16;
  int rowg = min(rbase + wrow + l16, nrows - 1);
  int lrow_v = (wrow + l16) * LSTR + quad * 8;
  bool wr = (rbase + wrow + l16 < nrows);

  bf16x8 avQ[4];
  {
    const unsigned short* arow = xb + (size_t)rowg * 128 + quad * 8;
#pragma unroll
    for (int kb = 0; kb < 4; kb++)
      avQ[kb] = *(const bf16x8*)(arow + kb * 32);
  }
#pragma unroll
  for (int c = 0; c < 3; c++) {
    floatx4 accQ[8];
#pragma unroll
    for (int ct = 0; ct < 8; ct++) accQ[ct] = (floatx4)(0.f);
#pragma unroll
    for (int kb = 0; kb < 4; kb++) {
      int kq = kb * 4 + quad;
      bf16x8 bh[8];
#pragma unroll
      for (int ct = 0; ct < 8; ct++)
        bh[ct] = *(const bf16x8*)&wqkv[(size_t)(kq * 384 + c * 128 + ct * 16 + l16) * 8];
#pragma unroll
      for (int ct = 0; ct < 8; ct++)
        accQ[ct] = __builtin_amdgcn_mfma_f32_16x16x32_bf16(avQ[kb], bh[ct], accQ[ct], 0, 0, 0);
    }
    const float* bias = (c == 0) ? bq : (c == 1) ? bk : bv;
#pragma unroll
    for (int ct = 0; ct < 8; ct++) {
      float bvv = bias[ct * 16 + l16];
#pragma unroll
      for (int i = 0; i < 4; i++)
        XR[(wrow + quad * 4 + i) * LSTR + ct * 16 + l16] = f2bf(accQ[ct][i] + bvv);
    }
    if (wr) {
      if (c == 0) {
#pragma unroll
        for (int kb = 0; kb < 4; kb++)
          *(bf16x8*)&qkv[(size_t)(rbase + wrow + l16) * 256 + kb * 32 + quad * 8] =
              *(bf16x8*)&XR[lrow_v + kb * 32];
      } else {
#pragma unroll
        for (int kb = 0; kb < 4; kb++) {
          bf16x8 w = *(bf16x8*)&XR[lrow_v + kb * 32];
          int p0 = __builtin_amdgcn_cvt_pk_fp8_f32(
              bf2f((unsigned short)w[0]) * 8.f, bf2f((unsigned short)w[1]) * 8.f, 0, false);
          int p1 = __builtin_amdgcn_cvt_pk_fp8_f32(
              bf2f((unsigned short)w[2]) * 8.f, bf2f((unsigned short)w[3]) * 8.f, 0, false);
          int p2 = __builtin_amdgcn_cvt_pk_fp8_f32(
              bf2f((unsigned short)w[4]) * 8.f, bf2f((unsigned short)w[5]) * 8.f, 0, false);
          int p3 = __builtin_amdgcn_cvt_pk_fp8_f32(
              bf2f((unsigned short)w[6]) * 8.f, bf2f((unsigned short)w[7]) * 8.f, 0, false);
          int2 st;
          st.x = (p0 & 0xffff) | (p1 << 16);
          st.y = (p2 & 0xffff) | (p3 << 16);
          *(int2*)&qkv[(size_t)(rbase + wrow + l16) * 256 + 128 + (c - 1) * 64 +
                       kb * 16 + quad * 4] = st;
        }
      }
    }
  }
}

// ================ chainA: attn + O-GEMM+LN1+FFN1+FFN2+LN2(+QKV next) ================
// 64 rows/block, 4 waves x 16 rows, barrier-free. Attn for own rows (2 nodes/pass,
// 32 lanes/node, 8 passes) -> F (per-wave private, bf16 = old `a` bits). Residual
// xb read scattered (R11: staging neutral). ffh lives in F; x1 in registers.
#define ATTN_C8 0.04508422003f   // 0.25*log2(e)/8
#define ATTN_L  7.21347520444f
__device__ __forceinline__ float edge_score8(float p) {
  float t = fminf(fmaxf(p * ATTN_C8, -ATTN_L), ATTN_L);
  return __builtin_amdgcn_exp2f(t);
}
template<bool LAST>
__global__ __launch_bounds__(256) void chainA_kernel(
    const unsigned short* __restrict__ qkv_in,
    const int* __restrict__ offsets, const int* __restrict__ csr,
    unsigned short* __restrict__ xb,
    unsigned short* __restrict__ qkv_out,
    const unsigned short* __restrict__ wo, const float* __restrict__ bo,
    const float* __restrict__ g1, const float* __restrict__ be1,
    const unsigned short* __restrict__ wf1, const float* __restrict__ bf1,
    const unsigned short* __restrict__ wf2, const float* __restrict__ bf2,
    const float* __restrict__ g2, const float* __restrict__ be2,
    const unsigned short* __restrict__ wqkv,
    const float* __restrict__ bq, const float* __restrict__ bk,
    const float* __restrict__ bv, int nrows)
{
  __shared__ unsigned short Y[64 * LSTR];  // y, then x2
  __shared__ unsigned short F[64 * LSTR];  // attn-out, then ffh halves, then qkv staging
  int tid = threadIdx.x;
  int wave = tid >> 6, lane = tid & 63;
  int quad = lane >> 4, l16 = lane & 15;
  int half = lane >> 5, l32 = lane & 31;
  int rbase = blockIdx.x * 64;
  int wrow = wave * 16;
  int rowg = min(rbase + wrow + l16, nrows - 1);
  int lrow_v = (wrow + l16) * LSTR + quad * 8;
  bool wr = (rbase + wrow + l16 < nrows);

  // ---- attn phase: 8 passes x 2 nodes/wave -> F rows ----
  {
    const unsigned short* kb8 = qkv_in + 128 + l32 * 2;
    const unsigned short* vb8 = qkv_in + 192 + l32 * 2;
#pragma unroll 1
    for (int p = 0; p < 8; p++) {
      int nodeL = wrow + p * 2 + half;          // local row
      int node = rbase + nodeL;
      if (node >= nrows) node = nrows - 1;      // clamp: duplicate compute, row write stays local
      float q0, q1, q2v, q3;
      {
        ushort4 qu = *(const ushort4*)(qkv_in + (size_t)node * 256 + l32 * 4);
        q0 = bf2f(qu.x); q1 = bf2f(qu.y); q2v = bf2f(qu.z); q3 = bf2f(qu.w);
      }
      float w0 = 0.f, w1 = 0.f, w2 = 0.f, w3 = 0.f, z = 0.f;
      int j = offsets[node], end = offsets[node + 1];
      for (; j + 4 <= end; j += 4) {
        int s[4];
#pragma unroll
        for (int u = 0; u < 4; u++) s[u] = csr[j + u] << 8;
        unsigned int ku[4], vu[4];
#pragma unroll
        for (int u = 0; u < 4; u++) {
          ku[u] = *(const unsigned int*)(kb8 + s[u]);
          vu[u] = *(const unsigned int*)(vb8 + s[u]);
        }
        float pp[4];
#pragma unroll
        for (int u = 0; u < 4; u++) {
          floatx2 ka = __builtin_amdgcn_cvt_pk_f32_fp8((int)ku[u], false);
          floatx2 kc = __builtin_amdgcn_cvt_pk_f32_fp8((int)ku[u], true);
          pp[u] = fmaf(ka[0], q0, fmaf(ka[1], q1, fmaf(kc[0], q2v, kc[1] * q3)));
        }
#pragma unroll
        for (int u = 0; u < 4; u++) pp[u] += __shfl_xor(pp[u], 1);
#pragma unroll
        for (int u = 0; u < 4; u++) pp[u] += __shfl_xor(pp[u], 2);
#pragma unroll
        for (int u = 0; u < 4; u++) {
          float sc = edge_score8(pp[u]);
          floatx2 va = __builtin_amdgcn_cvt_pk_f32_fp8((int)vu[u], false);
          floatx2 vc = __builtin_amdgcn_cvt_pk_f32_fp8((int)vu[u], true);
          w0 = fmaf(sc, va[0], w0); w1 = fmaf(sc, va[1], w1);
          w2 = fmaf(sc, vc[0], w2); w3 = fmaf(sc, vc[1], w3);
          z += sc;
        }
      }
      for (; j < end; ++j) {
        int s = csr[j] << 8;
        unsigned int ku = *(const unsigned int*)(kb8 + s);
        unsigned int vu = *(const unsigned int*)(vb8 + s);
        floatx2 ka = __builtin_amdgcn_cvt_pk_f32_fp8((int)ku, false);
        floatx2 kc = __builtin_amdgcn_cvt_pk_f32_fp8((int)ku, true);
        float pv = fmaf(ka[0], q0, fmaf(ka[1], q1, fmaf(kc[0], q2v, kc[1] * q3)));
        pv += __shfl_xor(pv, 1); pv += __shfl_xor(pv, 2);
        float sc = edge_score8(pv);
        floatx2 va = __builtin_amdgcn_cvt_pk_f32_fp8((int)vu, false);
        floatx2 vc = __builtin_amdgcn_cvt_pk_f32_fp8((int)vu, true);
        w0 = fmaf(sc, va[0], w0); w1 = fmaf(sc, va[1], w1);
        w2 = fmaf(sc, vc[0], w2); w3 = fmaf(sc, vc[1], w3);
        z += sc;
      }
      float inv = 1.f / (8.f * z + 8e-6f);
      ushort4 pk;
      pk.x = f2bf(w0 * inv); pk.y = f2bf(w1 * inv);
      pk.z = f2bf(w2 * inv); pk.w = f2bf(w3 * inv);
      *(ushort4*)&F[nodeL * LSTR + l32 * 4] = pk;
    }
  }

  // ---- A-frags for O-GEMM from F (before FFN1 reuses F) ----
  bf16x8 avO[4];
#pragma unroll
  for (int kb = 0; kb < 4; kb++)
    avO[kb] = *(bf16x8*)&F[lrow_v + kb * 32];

  // ---- O-GEMM ----
  floatx4 accO[8];
#pragma unroll
  for (int cc = 0; cc < 8; cc++) accO[cc] = (floatx4)(0.f);
#pragma unroll
  for (int kb = 0; kb < 4; kb++) {
    int kq = kb * 4 + quad;
    bf16x8 bh[8];
#pragma unroll
    for (int cc = 0; cc < 8; cc++)
      bh[cc] = *(const bf16x8*)&wo[(size_t)(kq * 128 + cc * 16 + l16) * 8];
#pragma unroll
    for (int cc = 0; cc < 8; cc++)
      accO[cc] = __builtin_amdgcn_mfma_f32_16x16x32_bf16(avO[kb], bh[cc], accO[cc], 0, 0, 0);
  }

  // ---- LN1: x1 -> registers (bf16-rounded); y -> Y; xb read scattered ----
  float x1v[8][4];
  {
    float biasO[8], g1v[8], b1v[8];
#pragma unroll
    for (int cc = 0; cc < 8; cc++) {
      int col = cc * 16 + l16;
      biasO[cc] = bo[col]; g1v[cc] = g1[col]; b1v[cc] = be1[col];
    }
#pragma unroll
    for (int i = 0; i < 4; i++) {
      int lrow = wrow + quad * 4 + i;
      int growc = min(rbase + lrow, nrows - 1);
      float t[8]; float s = 0.f;
#pragma unroll
      for (int cc = 0; cc < 8; cc++) {
        float yv = accO[cc][i] + biasO[cc];
        Y[lrow * LSTR + cc * 16 + l16] = f2bf(yv);
        t[cc] = yv + bf2f(xb[(size_t)growc * 128 + cc * 16 + l16]);
        s += t[cc];
      }
      s += __shfl_xor(s, 1); s += __shfl_xor(s, 2);
      s += __shfl_xor(s, 4); s += __shfl_xor(s, 8);
      float mean = s * (1.f / 128.f);
      float vv = 0.f;
#pragma unroll
      for (int cc = 0; cc < 8; cc++) { float d = t[cc] - mean; vv += d * d; }
      vv += __shfl_xor(vv, 1); vv += __shfl_xor(vv, 2);
      vv += __shfl_xor(vv, 4); vv += __shfl_xor(vv, 8);
      float inv = rsqrtf(vv * (1.f / 128.f) + 1e-5f);
#pragma unroll
      for (int cc = 0; cc < 8; cc++)
        x1v[cc][i] = bf2f(f2bf((t[cc] - mean) * inv * g1v[cc] + b1v[cc]));
    }
  }

  // ---- FFN1 + FFN2 interleaved (ffh halves through F) ----
  bf16x8 avY[4];
#pragma unroll
  for (int kb = 0; kb < 4; kb++)
    avY[kb] = *(bf16x8*)&Y[lrow_v + kb * 32];
  floatx4 acc2[8];
#pragma unroll
  for (int cc = 0; cc < 8; cc++) acc2[cc] = (floatx4)(0.f);
#pragma unroll
  for (int h = 0; h < 2; h++) {
    floatx4 accF[8];
#pragma unroll
    for (int cc = 0; cc < 8; cc++) accF[cc] = (floatx4)(0.f);
#pragma unroll
    for (int kb = 0; kb < 4; kb++) {
      int kq = kb * 4 + quad;
      bf16x8 bh[8];
#pragma unroll
      for (int cc = 0; cc < 8; cc++)
        bh[cc] = *(const bf16x8*)&wf1[(size_t)(kq * 256 + h * 128 + cc * 16 + l16) * 8];
#pragma unroll
      for (int cc = 0; cc < 8; cc++)
        accF[cc] = __builtin_amdgcn_mfma_f32_16x16x32_bf16(avY[kb], bh[cc], accF[cc], 0, 0, 0);
    }
#pragma unroll
    for (int i = 0; i < 4; i++) {
      int lrow = wrow + quad * 4 + i;
#pragma unroll
      for (int cc = 0; cc < 8; cc++)
        F[lrow * LSTR + cc * 16 + l16] =
            f2bf(fmaxf(accF[cc][i] + bf1[h * 128 + cc * 16 + l16], 0.f));
    }
#pragma unroll
    for (int kb = 0; kb < 4; kb++) {
      bf16x8 avF = *(bf16x8*)&F[lrow_v + kb * 32];
      int kq = h * 16 + kb * 4 + quad;
      bf16x8 bh[8];
#pragma unroll
      for (int cc = 0; cc < 8; cc++)
        bh[cc] = *(const bf16x8*)&wf2[(size_t)(kq * 128 + cc * 16 + l16) * 8];
#pragma unroll
      for (int cc = 0; cc < 8; cc++)
        acc2[cc] = __builtin_amdgcn_mfma_f32_16x16x32_bf16(avF, bh[cc], acc2[cc], 0, 0, 0);
    }
  }

  // ---- LN2: x2 = LN(x1 + ffn2) -> Y + xb ----
  {
    float bias2[8], g2v[8], b2v[8];
#pragma unroll
    for (int cc = 0; cc < 8; cc++) {
      int col = cc * 16 + l16;
      bias2[cc] = bf2[col]; g2v[cc] = g2[col]; b2v[cc] = be2[col];
    }
#pragma unroll
    for (int i = 0; i < 4; i++) {
      int lrow = wrow + quad * 4 + i;
      float t[8]; float s = 0.f;
#pragma unroll
      for (int cc = 0; cc < 8; cc++) {
        t[cc] = acc2[cc][i] + bias2[cc] + x1v[cc][i];
        s += t[cc];
      }
      s += __shfl_xor(s, 1); s += __shfl_xor(s, 2);
      s += __shfl_xor(s, 4); s += __shfl_xor(s, 8);
      float mean = s * (1.f / 128.f);
      float vv = 0.f;
#pragma unroll
      for (int cc = 0; cc < 8; cc++) { float d = t[cc] - mean; vv += d * d; }
      vv += __shfl_xor(vv, 1); vv += __shfl_xor(vv, 2);
      vv += __shfl_xor(vv, 4); vv += __shfl_xor(vv, 8);
      float inv = rsqrtf(vv * (1.f / 128.f) + 1e-5f);
#pragma unroll
      for (int cc = 0; cc < 8; cc++)
        Y[lrow * LSTR + cc * 16 + l16] =
            f2bf((t[cc] - mean) * inv * g2v[cc] + b2v[cc]);
    }
  }
  if (wr) {
#pragma unroll
    for (int kb = 0; kb < 4; kb++)
      *(bf16x8*)&xb[(size_t)(rbase + wrow + l16) * 128 + kb * 32 + quad * 8] =
          *(bf16x8*)&Y[lrow_v + kb * 32];
  }

  // ---- QKV next (A from Y, out staged via F) ----
  if (!LAST) {
    bf16x8 avQ[4];
#pragma unroll
    for (int kb = 0; kb < 4; kb++)
      avQ[kb] = *(bf16x8*)&Y[lrow_v + kb * 32];
#pragma unroll
    for (int c = 0; c < 3; c++) {
      floatx4 accQ[8];
#pragma unroll
      for (int ct = 0; ct < 8; ct++) accQ[ct] = (floatx4)(0.f);
#pragma unroll
      for (int kb = 0; kb < 4; kb++) {
        int kq = kb * 4 + quad;
        bf16x8 bh[8];
#pragma unroll
        for (int ct = 0; ct < 8; ct++)
          bh[ct] = *(const bf16x8*)&wqkv[(size_t)(kq * 384 + c * 128 + ct * 16 + l16) * 8];
#pragma unroll
        for (int ct = 0; ct < 8; ct++)
          accQ[ct] = __builtin_amdgcn_mfma_f32_16x16x32_bf16(avQ[kb], bh[ct], accQ[ct], 0, 0, 0);
      }
      const float* bias = (c == 0) ? bq : (c == 1) ? bk : bv;
#pragma unroll
      for (int ct = 0; ct < 8; ct++) {
        float bvv = bias[ct * 16 + l16];
#pragma unroll
        for (int i = 0; i < 4; i++)
          F[(wrow + quad * 4 + i) * LSTR + ct * 16 + l16] = f2bf(accQ[ct][i] + bvv);
      }
      if (wr) {
        if (c == 0) {
#pragma unroll
          for (int kb = 0; kb < 4; kb++)
            *(bf16x8*)&qkv_out[(size_t)(rbase + wrow + l16) * 256 + kb * 32 + quad * 8] =
                *(bf16x8*)&F[lrow_v + kb * 32];
        } else {
#pragma unroll
          for (int kb = 0; kb < 4; kb++) {
            bf16x8 w = *(bf16x8*)&F[lrow_v + kb * 32];
            int p0 = __builtin_amdgcn_cvt_pk_fp8_f32(
                bf2f((unsigned short)w[0]) * 8.f, bf2f((unsigned short)w[1]) * 8.f, 0, false);
            int p1 = __builtin_amdgcn_cvt_pk_fp8_f32(
                bf2f((unsigned short)w[2]) * 8.f, bf2f((unsigned short)w[3]) * 8.f, 0, false);
            int p2 = __builtin_amdgcn_cvt_pk_fp8_f32(
                bf2f((unsigned short)w[4]) * 8.f, bf2f((unsigned short)w[5]) * 8.f, 0, false);
            int p3 = __builtin_amdgcn_cvt_pk_fp8_f32(
                bf2f((unsigned short)w[6]) * 8.f, bf2f((unsigned short)w[7]) * 8.f, 0, false);
            int2 st;
            st.x = (p0 & 0xffff) | (p1 << 16);
            st.y = (p2 & 0xffff) | (p3 << 16);
            *(int2*)&qkv_out[(size_t)(rbase + wrow + l16) * 256 + 128 + (c - 1) * 64 +
                             kb * 16 + quad * 4] = st;
          }
        }
      }
    }
  }
}
#undef LSTR

// ---------------- column-sum stage 1: 128 blocks, NO atomics ----------------
#define CM_BLOCKS 128
__global__ __launch_bounds__(256) void colsum_partial(
    const unsigned short* __restrict__ xb, float* __restrict__ partial)
{
  int cg = threadIdx.x & 15;
  int ro = threadIdx.x >> 4;
  int rows = (N_NODES + CM_BLOCKS - 1) / CM_BLOCKS;
  int r0 = blockIdx.x * rows;
  int r1 = min(r0 + rows, N_NODES);
  float acc[8];
#pragma unroll
  for (int j = 0; j < 8; j++) acc[j] = 0.f;
  int r = r0 + ro;
  for (; r + 48 < r1; r += 64) {
    bf16x8 v0 = *(const bf16x8*)&xb[(size_t)r * 128 + cg * 8];
    bf16x8 v1 = *(const bf16x8*)&xb[(size_t)(r + 16) * 128 + cg * 8];
    bf16x8 v2 = *(const bf16x8*)&xb[(size_t)(r + 32) * 128 + cg * 8];
    bf16x8 v3 = *(const bf16x8*)&xb[(size_t)(r + 48) * 128 + cg * 8];
#pragma unroll
    for (int j = 0; j < 8; j++)
      acc[j] += (bf2f((unsigned short)v0[j]) + bf2f((unsigned short)v1[j])) +
                (bf2f((unsigned short)v2[j]) + bf2f((unsigned short)v3[j]));
  }
  for (; r < r1; r += 16) {
    bf16x8 v = *(const bf16x8*)&xb[(size_t)r * 128 + cg * 8];
#pragma unroll
    for (int j = 0; j < 8; j++) acc[j] += bf2f((unsigned short)v[j]);
  }
  __shared__ float s[16 * 128];
#pragma unroll
  for (int j = 0; j < 8; j++) s[ro * 128 + cg * 8 + j] = acc[j];
  __syncthreads();
#pragma unroll
  for (int step = 8; step >= 1; step >>= 1) {
    if (ro < step) {
#pragma unroll
      for (int j = 0; j < 8; j++)
        s[ro * 128 + cg * 8 + j] += s[(ro + step) * 128 + cg * 8 + j];
    }
    __syncthreads();
  }
  if (ro < 2) {
    int c = ro * 64 + cg * 4;
    *(float4*)&partial[(size_t)blockIdx.x * 128 + c] = *(float4*)&s[c];
  }
}

// ---------------- readout MLP (with partial-reduction prologue) ----------------
__global__ void readout_kernel(
    const float* __restrict__ partial,
    const float* __restrict__ mW0, const float* __restrict__ mb0,
    const float* __restrict__ mW1, const float* __restrict__ mb1,
    const float* __restrict__ mW2, const float* __restrict__ mb2,
    float* __restrict__ out)
{
  __shared__ float sx[128], h0[64], h1[32];
  int t = threadIdx.x;
  {
    float s0 = 0.f, s1 = 0.f, s2 = 0.f, s3 = 0.f;
#pragma unroll 2
    for (int p = 0; p < CM_BLOCKS; p += 4) {
      s0 += partial[(size_t)p * 128 + t];
      s1 += partial[(size_t)(p + 1) * 128 + t];
      s2 += partial[(size_t)(p + 2) * 128 + t];
      s3 += partial[(size_t)(p + 3) * 128 + t];
    }
    sx[t] = ((s0 + s1) + (s2 + s3)) * (1.f / (float)N_NODES);
  }
  __syncthreads();
  if (t < 64) {
    float a = mb0[t];
    for (int i = 0; i < 128; i++) a = fmaf(sx[i], mW0[i * 64 + t], a);
    h0[t] = fmaxf(a, 0.f);
  }
  __syncthreads();
  if (t < 32) {
    float a = mb1[t];
    for (int i = 0; i < 64; i++) a = fmaf(h0[i], mW1[i * 32 + t], a);
    h1[t] = fmaxf(a, 0.f);
  }
  __syncthreads();
  if (t < 10) {
    float a = mb2[t];
    for (int i = 0; i < 32; i++) a = fmaf(h1[i], mW2[i * 10 + t], a);
    out[t] = a;
  }
}

extern "C" void kernel_launch(void* const* d_in, const int* in_sizes, int n_in,
                              void* d_out, int out_size, void* d_ws, size_t ws_size,
                              hipStream_t stream) {
  const int*   x_idx = (const int*)d_in[0];
  const int*   eidx  = (const int*)d_in[1];
  const float* emb   = (const float*)d_in[2];
  const float* Wq = (const float*)d_in[3];  const float* bq = (const float*)d_in[4];
  const float* Wk = (const float*)d_in[5];  const float* bk = (const float*)d_in[6];
  const float* Wv = (const float*)d_in[7];  const float* bv = (const float*)d_in[8];
  const float* Wo = (const float*)d_in[9];  const float* bo = (const float*)d_in[10];
  const float* g1 = (const float*)d_in[11]; const float* be1 = (const float*)d_in[12];
  const float* Wf1 = (const float*)d_in[13]; const float* bf1 = (const float*)d_in[14];
  const float* Wf2 = (const float*)d_in[15]; const float* bf2 = (const float*)d_in[16];
  const float* g2 = (const float*)d_in[17]; const float* be2 = (const float*)d_in[18];
  const float* mW0 = (const float*)d_in[19]; const float* mb0 = (const float*)d_in[20];
  const float* mW1 = (const float*)d_in[21]; const float* mb1 = (const float*)d_in[22];
  const float* mW2 = (const float*)d_in[23]; const float* mb2 = (const float*)d_in[24];
  float* out = (float*)d_out;

  const size_t NX = (size_t)N_NODES * DIM;
  unsigned short* xb   = (unsigned short*)d_ws;
  unsigned short* qkvA = xb + NX;                       // double-buffered qkv
  unsigned short* qkvB = qkvA + (size_t)N_NODES * 256;

  unsigned short* wqkv_p = qkvB + (size_t)N_NODES * 256;
  unsigned short* wo_p   = wqkv_p + 3 * 128 * 384;
  unsigned short* wf1_p  = wo_p   + 3 * 128 * 128;
  unsigned short* wf2_p  = wf1_p  + 3 * 128 * 256;
  unsigned short* wend   = wf2_p  + 3 * 256 * 128;

  int* counts    = (int*)wend;
  float* partial = (float*)(counts + N_NODES);
  int* offsets   = (int*)(partial + CM_BLOCKS * 128);
  int* bsums     = offsets + N_NODES + 1;
  int* csr       = bsums + 256;
  int* rank      = csr + N_EDGES;

  const int* e0 = eidx;
  const int* e1 = eidx + N_EDGES;

  hipMemsetAsync(counts, 0, N_NODES * sizeof(int), stream);

  prep_all<<<192, 256, 0, stream>>>(Wq, Wk, Wv, Wo, Wf1, Wf2,
                                    wqkv_p, wo_p, wf1_p, wf2_p);

  embed_kernel<<<(N_NODES * 32 + 255) / 256, 256, 0, stream>>>(x_idx, emb, xb);
  hist_kernel<<<(N_EDGES + 255) / 256, 256, 0, stream>>>(e1, counts, rank);
  int nblk = (N_NODES + 255) / 256;
  scan_local<<<nblk, 256, 0, stream>>>(counts, offsets, bsums);
  scan_bsums<<<1, 256, 0, stream>>>(bsums, nblk);
  scan_add<<<nblk, 256, 0, stream>>>(offsets, bsums);
  scatter_kernel<<<(N_EDGES + 255) / 256, 256, 0, stream>>>(e0, e1, offsets, rank, csr);

  int gc = (N_NODES + 63) / 64;

  qkv0_kernel<<<gc, 256, 0, stream>>>(xb, wqkv_p, bq, bk, bv, qkvA, N_NODES);

  for (int l = 0; l < NLAYERS; ++l) {
    const unsigned short* wo_l   = wo_p   + (size_t)l * 128 * 128;
    const unsigned short* wf1_l  = wf1_p  + (size_t)l * 128 * 256;
    const unsigned short* wf2_l  = wf2_p  + (size_t)l * 256 * 128;
    const unsigned short* wqkv_n = wqkv_p + (size_t)(l + 1) * 128 * 384;
    const float* bo_l  = bo  + (size_t)l * DIM;
    const float* g1_l  = g1  + (size_t)l * DIM;
    const float* be1_l = be1 + (size_t)l * DIM;
    const float* bf1_l = bf1 + (size_t)l * 2 * DIM;
    const float* bf2_l = bf2 + (size_t)l * DIM;
    const float* g2_l  = g2  + (size_t)l * DIM;
    const float* be2_l = be2 + (size_t)l * DIM;
    unsigned short* qin  = (l & 1) ? qkvB : qkvA;
    unsigned short* qout = (l & 1) ? qkvA : qkvB;

    if (l < NLAYERS - 1) {
      chainA_kernel<false><<<gc, 256, 0, stream>>>(
          qin, offsets, csr, xb, qout, wo_l, bo_l, g1_l, be1_l,
          wf1_l, bf1_l, wf2_l, bf2_l, g2_l, be2_l, wqkv_n,
          bq + (size_t)(l + 1) * DIM, bk + (size_t)(l + 1) * DIM,
          bv + (size_t)(l + 1) * DIM, N_NODES);
    } else {
      chainA_kernel<true><<<gc, 256, 0, stream>>>(
          qin, offsets, csr, xb, qout, wo_l, bo_l, g1_l, be1_l,
          wf1_l, bf1_l, wf2_l, bf2_l, g2_l, be2_l, wqkv_p,
          bq, bk, bv, N_NODES);
    }
  }

  colsum_partial<<<CM_BLOCKS, 256, 0, stream>>>(xb, partial);
  readout_kernel<<<1, 128, 0, stream>>>(partial, mW0, mb0, mW1, mb1, mW2, mb2, out);
}

// Round 21
// 442.243 us; speedup vs baseline: 1.6392x; 1.6392x over previous
//
#include <hip/hip_runtime.h>
#include <hip/hip_bf16.h>

#define N_NODES 50000
#define N_EDGES 800000
#define DIM 128
#define NLAYERS 3

typedef short bf16x8 __attribute__((ext_vector_type(8)));
typedef float floatx4 __attribute__((ext_vector_type(4)));
typedef float floatx2 __attribute__((ext_vector_type(2)));

__device__ __forceinline__ unsigned short f2bf(float f) {
  unsigned int u = __builtin_bit_cast(unsigned int, f);
  return (unsigned short)((u + 0x7FFFu + ((u >> 16) & 1u)) >> 16);
}
__device__ __forceinline__ float bf2f(unsigned short h) {
  return __builtin_bit_cast(float, (unsigned int)h << 16);
}

// ---------------- embedding gather -> bf16 residual ----------------
__global__ __launch_bounds__(256) void embed_kernel(
    const int* __restrict__ idx, const float* __restrict__ emb,
    unsigned short* __restrict__ xb)
{
  int gid = blockIdx.x * 256 + threadIdx.x;
  int n = gid >> 5;
  int c = (gid & 31) << 2;
  if (n >= N_NODES) return;
  int e = idx[n];
  float4 val = *(const float4*)(emb + (size_t)e * DIM + c);
  ushort4 pk;
  pk.x = f2bf(val.x); pk.y = f2bf(val.y); pk.z = f2bf(val.z); pk.w = f2bf(val.w);
  *(ushort4*)(xb + (size_t)n * DIM + c) = pk;
}

// ---------------- CSR build ----------------
__global__ __launch_bounds__(256) void hist_kernel(
    const int* __restrict__ e1, int* __restrict__ counts,
    int* __restrict__ rank)
{
  int i = blockIdx.x * 256 + threadIdx.x;
  if (i < N_EDGES) rank[i] = atomicAdd(&counts[e1[i]], 1);
}

__global__ __launch_bounds__(256) void scan_local(
    const int* __restrict__ counts, int* __restrict__ offsets,
    int* __restrict__ bsums)
{
  __shared__ int buf[256];
  int t = threadIdx.x;
  int i = blockIdx.x * 256 + t;
  int v = (i < N_NODES) ? counts[i] : 0;
  buf[t] = v;
  __syncthreads();
  int s = v;
#pragma unroll
  for (int off = 1; off < 256; off <<= 1) {
    int t2 = (t >= off) ? buf[t - off] : 0;
    __syncthreads();
    s += t2;
    buf[t] = s;
    __syncthreads();
  }
  if (i < N_NODES) offsets[i] = s - v;
  if (t == 255) bsums[blockIdx.x] = s;
}

__global__ void scan_bsums(int* __restrict__ bsums, int nblk)
{
  __shared__ int buf[256];
  int t = threadIdx.x;
  int v = (t < nblk) ? bsums[t] : 0;
  buf[t] = v;
  __syncthreads();
  int s = v;
#pragma unroll
  for (int off = 1; off < 256; off <<= 1) {
    int t2 = (t >= off) ? buf[t - off] : 0;
    __syncthreads();
    s += t2;
    buf[t] = s;
    __syncthreads();
  }
  if (t < nblk) bsums[t] = s - v;
}

__global__ __launch_bounds__(256) void scan_add(
    int* __restrict__ offsets, const int* __restrict__ bsums)
{
  int i = blockIdx.x * 256 + threadIdx.x;
  if (i < N_NODES) offsets[i] += bsums[blockIdx.x];
  if (i == 0) offsets[N_NODES] = N_EDGES;
}

__global__ __launch_bounds__(256) void scatter_kernel(
    const int* __restrict__ e0, const int* __restrict__ e1,
    const int* __restrict__ offsets, const int* __restrict__ rank,
    int* __restrict__ csr)
{
  int i = blockIdx.x * 256 + threadIdx.x;
  if (i >= N_EDGES) return;
  csr[offsets[e1[i]] + rank[i]] = e0[i];
}

// ---------------- combined weight prep (single-plane bf16, frag-major) ----------------
__global__ __launch_bounds__(256) void prep_all(
    const float* __restrict__ Wq, const float* __restrict__ Wk,
    const float* __restrict__ Wv, const float* __restrict__ Wo,
    const float* __restrict__ Wf1, const float* __restrict__ Wf2,
    unsigned short* __restrict__ wqkv, unsigned short* __restrict__ wo,
    unsigned short* __restrict__ wf1, unsigned short* __restrict__ wf2)
{
  int g = blockIdx.x * 256 + threadIdx.x;
  if (g < 18432) {
    int srcId = g / 6144; int rem = g - srcId * 6144;
    const float* W = (srcId == 0) ? Wq : (srcId == 1) ? Wk : Wv;
    int l = rem / 2048; int r2 = rem & 2047; int kq = r2 >> 7; int n = r2 & 127;
    const float* Wl = W + (size_t)l * 128 * 128;
    unsigned short* base = wqkv + (size_t)l * 128 * 384 + (size_t)(kq * 384 + srcId * 128 + n) * 8;
#pragma unroll
    for (int j = 0; j < 8; j++)
      base[j] = f2bf(Wl[(size_t)(kq * 8 + j) * 128 + n]);
    return;
  }
  g -= 18432;
  if (g < 6144) {
    int l = g / 2048; int r2 = g & 2047; int kq = r2 >> 7; int n = r2 & 127;
    const float* Wl = Wo + (size_t)l * 128 * 128;
    unsigned short* base = wo + (size_t)l * 128 * 128 + (size_t)(kq * 128 + n) * 8;
#pragma unroll
    for (int j = 0; j < 8; j++)
      base[j] = f2bf(Wl[(size_t)(kq * 8 + j) * 128 + n]);
    return;
  }
  g -= 6144;
  if (g < 12288) {
    int l = g / 4096; int r2 = g & 4095; int kq = r2 >> 8; int n = r2 & 255;
    const float* Wl = Wf1 + (size_t)l * 128 * 256;
    unsigned short* base = wf1 + (size_t)l * 128 * 256 + (size_t)(kq * 256 + n) * 8;
#pragma unroll
    for (int j = 0; j < 8; j++)
      base[j] = f2bf(Wl[(size_t)(kq * 8 + j) * 256 + n]);
    return;
  }
  g -= 12288;
  if (g < 12288) {
    int l = g / 4096; int r2 = g & 4095; int kq = r2 >> 7; int n = r2 & 127;
    const float* Wl = Wf2 + (size_t)l * 256 * 128;
    unsigned short* base = wf2 + (size_t)l * 256 * 128 + (size_t)(kq * 128 + n) * 8;
#pragma unroll
    for (int j = 0; j < 8; j++)
      base[j] = f2bf(Wl[(size_t)(kq * 8 + j) * 128 + n]);
  }
}

#define LSTR 136

// ---------------- layer-0 QKV (chain2-style, LDS-staged vector stores) ----------------
__global__ __launch_bounds__(256) void qkv0_kernel(
    const unsigned short* __restrict__ xb,
    const unsigned short* __restrict__ wqkv,
    const float* __restrict__ bq, const float* __restrict__ bk,
    const float* __restrict__ bv,
    unsigned short* __restrict__ qkv, int nrows)
{
  __shared__ unsigned short XR[64 * LSTR];
  int tid = threadIdx.x;
  int wave = tid >> 6, lane = tid & 63;
  int quad = lane >> 4, l16 = lane & 15;
  int rbase = blockIdx.x * 64;
  int wrow = wave * 16;
  int rowg = min(rbase + wrow + l16, nrows - 1);
  int lrow_v = (wrow + l16) * LSTR + quad * 8;
  bool wr = (rbase + wrow + l16 < nrows);

  bf16x8 avQ[4];
  {
    const unsigned short* arow = xb + (size_t)rowg * 128 + quad * 8;
#pragma unroll
    for (int kb = 0; kb < 4; kb++)
      avQ[kb] = *(const bf16x8*)(arow + kb * 32);
  }
#pragma unroll
  for (int c = 0; c < 3; c++) {
    floatx4 accQ[8];
#pragma unroll
    for (int ct = 0; ct < 8; ct++) accQ[ct] = (floatx4)(0.f);
#pragma unroll
    for (int kb = 0; kb < 4; kb++) {
      int kq = kb * 4 + quad;
      bf16x8 bh[8];
#pragma unroll
      for (int ct = 0; ct < 8; ct++)
        bh[ct] = *(const bf16x8*)&wqkv[(size_t)(kq * 384 + c * 128 + ct * 16 + l16) * 8];
#pragma unroll
      for (int ct = 0; ct < 8; ct++)
        accQ[ct] = __builtin_amdgcn_mfma_f32_16x16x32_bf16(avQ[kb], bh[ct], accQ[ct], 0, 0, 0);
    }
    const float* bias = (c == 0) ? bq : (c == 1) ? bk : bv;
#pragma unroll
    for (int ct = 0; ct < 8; ct++) {
      float bvv = bias[ct * 16 + l16];
#pragma unroll
      for (int i = 0; i < 4; i++)
        XR[(wrow + quad * 4 + i) * LSTR + ct * 16 + l16] = f2bf(accQ[ct][i] + bvv);
    }
    if (wr) {
      if (c == 0) {
#pragma unroll
        for (int kb = 0; kb < 4; kb++)
          *(bf16x8*)&qkv[(size_t)(rbase + wrow + l16) * 256 + kb * 32 + quad * 8] =
              *(bf16x8*)&XR[lrow_v + kb * 32];
      } else {
#pragma unroll
        for (int kb = 0; kb < 4; kb++) {
          bf16x8 w = *(bf16x8*)&XR[lrow_v + kb * 32];
          int p0 = __builtin_amdgcn_cvt_pk_fp8_f32(
              bf2f((unsigned short)w[0]) * 8.f, bf2f((unsigned short)w[1]) * 8.f, 0, false);
          int p1 = __builtin_amdgcn_cvt_pk_fp8_f32(
              bf2f((unsigned short)w[2]) * 8.f, bf2f((unsigned short)w[3]) * 8.f, 0, false);
          int p2 = __builtin_amdgcn_cvt_pk_fp8_f32(
              bf2f((unsigned short)w[4]) * 8.f, bf2f((unsigned short)w[5]) * 8.f, 0, false);
          int p3 = __builtin_amdgcn_cvt_pk_fp8_f32(
              bf2f((unsigned short)w[6]) * 8.f, bf2f((unsigned short)w[7]) * 8.f, 0, false);
          int2 st;
          st.x = (p0 & 0xffff) | (p1 << 16);
          st.y = (p2 & 0xffff) | (p3 << 16);
          *(int2*)&qkv[(size_t)(rbase + wrow + l16) * 256 + 128 + (c - 1) * 64 +
                       kb * 16 + quad * 4] = st;
        }
      }
    }
  }
}

// ================ merged chain: O-GEMM+LN1+FFN1+FFN2+LN2(+QKV next) ================
template<bool LAST>
__global__ __launch_bounds__(256) void chainM_kernel(
    const unsigned short* __restrict__ a,
    unsigned short* __restrict__ xb,
    unsigned short* __restrict__ qkv,
    const unsigned short* __restrict__ wo, const float* __restrict__ bo,
    const float* __restrict__ g1, const float* __restrict__ be1,
    const unsigned short* __restrict__ wf1, const float* __restrict__ bf1,
    const unsigned short* __restrict__ wf2, const float* __restrict__ bf2,
    const float* __restrict__ g2, const float* __restrict__ be2,
    const unsigned short* __restrict__ wqkv,
    const float* __restrict__ bq, const float* __restrict__ bk,
    const float* __restrict__ bv, int nrows)
{
  __shared__ unsigned short Y[64 * LSTR];  // y, then x2
  __shared__ unsigned short F[64 * LSTR];  // xb-in, then ffh halves, then qkv staging
  int tid = threadIdx.x;
  int wave = tid >> 6, lane = tid & 63;
  int quad = lane >> 4, l16 = lane & 15;
  int rbase = blockIdx.x * 64;
  int wrow = wave * 16;
  int rowg = min(rbase + wrow + l16, nrows - 1);
  int lrow_v = (wrow + l16) * LSTR + quad * 8;
  bool wr = (rbase + wrow + l16 < nrows);

#pragma unroll
  for (int kb = 0; kb < 4; kb++)
    *(bf16x8*)&F[lrow_v + kb * 32] =
        *(const bf16x8*)&xb[(size_t)rowg * 128 + kb * 32 + quad * 8];

  floatx4 accO[8];
#pragma unroll
  for (int cc = 0; cc < 8; cc++) accO[cc] = (floatx4)(0.f);
  {
    const unsigned short* arow = a + (size_t)rowg * 128 + quad * 8;
#pragma unroll
    for (int kb = 0; kb < 4; kb++) {
      bf16x8 av = *(const bf16x8*)(arow + kb * 32);
      int kq = kb * 4 + quad;
      bf16x8 bh[8];
#pragma unroll
      for (int cc = 0; cc < 8; cc++)
        bh[cc] = *(const bf16x8*)&wo[(size_t)(kq * 128 + cc * 16 + l16) * 8];
#pragma unroll
      for (int cc = 0; cc < 8; cc++)
        accO[cc] = __builtin_amdgcn_mfma_f32_16x16x32_bf16(av, bh[cc], accO[cc], 0, 0, 0);
    }
  }

  float x1v[8][4];
  {
    float biasO[8], g1v[8], b1v[8];
#pragma unroll
    for (int cc = 0; cc < 8; cc++) {
      int col = cc * 16 + l16;
      biasO[cc] = bo[col]; g1v[cc] = g1[col]; b1v[cc] = be1[col];
    }
#pragma unroll
    for (int i = 0; i < 4; i++) {
      int lrow = wrow + quad * 4 + i;
      float t[8]; float s = 0.f;
#pragma unroll
      for (int cc = 0; cc < 8; cc++) {
        float yv = accO[cc][i] + biasO[cc];
        Y[lrow * LSTR + cc * 16 + l16] = f2bf(yv);
        t[cc] = yv + bf2f(F[lrow * LSTR + cc * 16 + l16]);
        s += t[cc];
      }
      s += __shfl_xor(s, 1); s += __shfl_xor(s, 2);
      s += __shfl_xor(s, 4); s += __shfl_xor(s, 8);
      float mean = s * (1.f / 128.f);
      float vv = 0.f;
#pragma unroll
      for (int cc = 0; cc < 8; cc++) { float d = t[cc] - mean; vv += d * d; }
      vv += __shfl_xor(vv, 1); vv += __shfl_xor(vv, 2);
      vv += __shfl_xor(vv, 4); vv += __shfl_xor(vv, 8);
      float inv = rsqrtf(vv * (1.f / 128.f) + 1e-5f);
#pragma unroll
      for (int cc = 0; cc < 8; cc++)
        x1v[cc][i] = bf2f(f2bf((t[cc] - mean) * inv * g1v[cc] + b1v[cc]));
    }
  }

  bf16x8 avY[4];
#pragma unroll
  for (int kb = 0; kb < 4; kb++)
    avY[kb] = *(bf16x8*)&Y[lrow_v + kb * 32];
  floatx4 acc2[8];
#pragma unroll
  for (int cc = 0; cc < 8; cc++) acc2[cc] = (floatx4)(0.f);
#pragma unroll
  for (int h = 0; h < 2; h++) {
    floatx4 accF[8];
#pragma unroll
    for (int cc = 0; cc < 8; cc++) accF[cc] = (floatx4)(0.f);
#pragma unroll
    for (int kb = 0; kb < 4; kb++) {
      int kq = kb * 4 + quad;
      bf16x8 bh[8];
#pragma unroll
      for (int cc = 0; cc < 8; cc++)
        bh[cc] = *(const bf16x8*)&wf1[(size_t)(kq * 256 + h * 128 + cc * 16 + l16) * 8];
#pragma unroll
      for (int cc = 0; cc < 8; cc++)
        accF[cc] = __builtin_amdgcn_mfma_f32_16x16x32_bf16(avY[kb], bh[cc], accF[cc], 0, 0, 0);
    }
#pragma unroll
    for (int i = 0; i < 4; i++) {
      int lrow = wrow + quad * 4 + i;
#pragma unroll
      for (int cc = 0; cc < 8; cc++)
        F[lrow * LSTR + cc * 16 + l16] =
            f2bf(fmaxf(accF[cc][i] + bf1[h * 128 + cc * 16 + l16], 0.f));
    }
#pragma unroll
    for (int kb = 0; kb < 4; kb++) {
      bf16x8 avF = *(bf16x8*)&F[lrow_v + kb * 32];
      int kq = h * 16 + kb * 4 + quad;
      bf16x8 bh[8];
#pragma unroll
      for (int cc = 0; cc < 8; cc++)
        bh[cc] = *(const bf16x8*)&wf2[(size_t)(kq * 128 + cc * 16 + l16) * 8];
#pragma unroll
      for (int cc = 0; cc < 8; cc++)
        acc2[cc] = __builtin_amdgcn_mfma_f32_16x16x32_bf16(avF, bh[cc], acc2[cc], 0, 0, 0);
    }
  }

  {
    float bias2[8], g2v[8], b2v[8];
#pragma unroll
    for (int cc = 0; cc < 8; cc++) {
      int col = cc * 16 + l16;
      bias2[cc] = bf2[col]; g2v[cc] = g2[col]; b2v[cc] = be2[col];
    }
#pragma unroll
    for (int i = 0; i < 4; i++) {
      int lrow = wrow + quad * 4 + i;
      float t[8]; float s = 0.f;
#pragma unroll
      for (int cc = 0; cc < 8; cc++) {
        t[cc] = acc2[cc][i] + bias2[cc] + x1v[cc][i];
        s += t[cc];
      }
      s += __shfl_xor(s, 1); s += __shfl_xor(s, 2);
      s += __shfl_xor(s, 4); s += __shfl_xor(s, 8);
      float mean = s * (1.f / 128.f);
      float vv = 0.f;
#pragma unroll
      for (int cc = 0; cc < 8; cc++) { float d = t[cc] - mean; vv += d * d; }
      vv += __shfl_xor(vv, 1); vv += __shfl_xor(vv, 2);
      vv += __shfl_xor(vv, 4); vv += __shfl_xor(vv, 8);
      float inv = rsqrtf(vv * (1.f / 128.f) + 1e-5f);
#pragma unroll
      for (int cc = 0; cc < 8; cc++)
        Y[lrow * LSTR + cc * 16 + l16] =
            f2bf((t[cc] - mean) * inv * g2v[cc] + b2v[cc]);
    }
  }
  if (wr) {
#pragma unroll
    for (int kb = 0; kb < 4; kb++)
      *(bf16x8*)&xb[(size_t)(rbase + wrow + l16) * 128 + kb * 32 + quad * 8] =
          *(bf16x8*)&Y[lrow_v + kb * 32];
  }

  if (!LAST) {
    bf16x8 avQ[4];
#pragma unroll
    for (int kb = 0; kb < 4; kb++)
      avQ[kb] = *(bf16x8*)&Y[lrow_v + kb * 32];
#pragma unroll
    for (int c = 0; c < 3; c++) {
      floatx4 accQ[8];
#pragma unroll
      for (int ct = 0; ct < 8; ct++) accQ[ct] = (floatx4)(0.f);
#pragma unroll
      for (int kb = 0; kb < 4; kb++) {
        int kq = kb * 4 + quad;
        bf16x8 bh[8];
#pragma unroll
        for (int ct = 0; ct < 8; ct++)
          bh[ct] = *(const bf16x8*)&wqkv[(size_t)(kq * 384 + c * 128 + ct * 16 + l16) * 8];
#pragma unroll
        for (int ct = 0; ct < 8; ct++)
          accQ[ct] = __builtin_amdgcn_mfma_f32_16x16x32_bf16(avQ[kb], bh[ct], accQ[ct], 0, 0, 0);
      }
      const float* bias = (c == 0) ? bq : (c == 1) ? bk : bv;
#pragma unroll
      for (int ct = 0; ct < 8; ct++) {
        float bvv = bias[ct * 16 + l16];
#pragma unroll
        for (int i = 0; i < 4; i++)
          F[(wrow + quad * 4 + i) * LSTR + ct * 16 + l16] = f2bf(accQ[ct][i] + bvv);
      }
      if (wr) {
        if (c == 0) {
#pragma unroll
          for (int kb = 0; kb < 4; kb++)
            *(bf16x8*)&qkv[(size_t)(rbase + wrow + l16) * 256 + kb * 32 + quad * 8] =
                *(bf16x8*)&F[lrow_v + kb * 32];
        } else {
#pragma unroll
          for (int kb = 0; kb < 4; kb++) {
            bf16x8 w = *(bf16x8*)&F[lrow_v + kb * 32];
            int p0 = __builtin_amdgcn_cvt_pk_fp8_f32(
                bf2f((unsigned short)w[0]) * 8.f, bf2f((unsigned short)w[1]) * 8.f, 0, false);
            int p1 = __builtin_amdgcn_cvt_pk_fp8_f32(
                bf2f((unsigned short)w[2]) * 8.f, bf2f((unsigned short)w[3]) * 8.f, 0, false);
            int p2 = __builtin_amdgcn_cvt_pk_fp8_f32(
                bf2f((unsigned short)w[4]) * 8.f, bf2f((unsigned short)w[5]) * 8.f, 0, false);
            int p3 = __builtin_amdgcn_cvt_pk_fp8_f32(
                bf2f((unsigned short)w[6]) * 8.f, bf2f((unsigned short)w[7]) * 8.f, 0, false);
            int2 st;
            st.x = (p0 & 0xffff) | (p1 << 16);
            st.y = (p2 & 0xffff) | (p3 << 16);
            *(int2*)&qkv[(size_t)(rbase + wrow + l16) * 256 + 128 + (c - 1) * 64 +
                         kb * 16 + quad * 4] = st;
          }
        }
      }
    }
  }
}
#undef LSTR

// ---------------- fused edge attention: 2 nodes/wave, fp8 k/v ----------------
#define ATTN_C8 0.04508422003f   // 0.25*log2(e)/8
#define ATTN_L  7.21347520444f
__device__ __forceinline__ float edge_score8(float p) {
  float t = fminf(fmaxf(p * ATTN_C8, -ATTN_L), ATTN_L);
  return __builtin_amdgcn_exp2f(t);
}
__global__ __launch_bounds__(256) void attn_kernel(
    const unsigned short* __restrict__ qkv,
    const int* __restrict__ offsets, const int* __restrict__ csr,
    unsigned short* __restrict__ attn)
{
  int node = blockIdx.x * 8 + (threadIdx.x >> 5);
  int l32 = threadIdx.x & 31;
  if (node >= N_NODES) return;
  float q0, q1, q2v, q3;
  {
    ushort4 qu = *(const ushort4*)(qkv + (size_t)node * 256 + l32 * 4);
    q0 = bf2f(qu.x); q1 = bf2f(qu.y); q2v = bf2f(qu.z); q3 = bf2f(qu.w);
  }
  const unsigned short* kb8 = qkv + 128 + l32 * 2;
  const unsigned short* vb8 = qkv + 192 + l32 * 2;
  float w0 = 0.f, w1 = 0.f, w2 = 0.f, w3 = 0.f, z = 0.f;
  int j = offsets[node], end = offsets[node + 1];
  for (; j + 4 <= end; j += 4) {
    int s[4];
#pragma unroll
    for (int u = 0; u < 4; u++) s[u] = csr[j + u] << 8;
    unsigned int ku[4], vu[4];
#pragma unroll
    for (int u = 0; u < 4; u++) {
      ku[u] = *(const unsigned int*)(kb8 + s[u]);
      vu[u] = *(const unsigned int*)(vb8 + s[u]);
    }
    float p[4];
#pragma unroll
    for (int u = 0; u < 4; u++) {
      floatx2 ka = __builtin_amdgcn_cvt_pk_f32_fp8((int)ku[u], false);
      floatx2 kc = __builtin_amdgcn_cvt_pk_f32_fp8((int)ku[u], true);
      p[u] = fmaf(ka[0], q0, fmaf(ka[1], q1, fmaf(kc[0], q2v, kc[1] * q3)));
    }
#pragma unroll
    for (int u = 0; u < 4; u++) p[u] += __shfl_xor(p[u], 1);
#pragma unroll
    for (int u = 0; u < 4; u++) p[u] += __shfl_xor(p[u], 2);
#pragma unroll
    for (int u = 0; u < 4; u++) {
      float sc = edge_score8(p[u]);
      floatx2 va = __builtin_amdgcn_cvt_pk_f32_fp8((int)vu[u], false);
      floatx2 vc = __builtin_amdgcn_cvt_pk_f32_fp8((int)vu[u], true);
      w0 = fmaf(sc, va[0], w0); w1 = fmaf(sc, va[1], w1);
      w2 = fmaf(sc, vc[0], w2); w3 = fmaf(sc, vc[1], w3);
      z += sc;
    }
  }
  for (; j < end; ++j) {
    int s = csr[j] << 8;
    unsigned int ku = *(const unsigned int*)(kb8 + s);
    unsigned int vu = *(const unsigned int*)(vb8 + s);
    floatx2 ka = __builtin_amdgcn_cvt_pk_f32_fp8((int)ku, false);
    floatx2 kc = __builtin_amdgcn_cvt_pk_f32_fp8((int)ku, true);
    float p = fmaf(ka[0], q0, fmaf(ka[1], q1, fmaf(kc[0], q2v, kc[1] * q3)));
    p += __shfl_xor(p, 1); p += __shfl_xor(p, 2);
    float sc = edge_score8(p);
    floatx2 va = __builtin_amdgcn_cvt_pk_f32_fp8((int)vu, false);
    floatx2 vc = __builtin_amdgcn_cvt_pk_f32_fp8((int)vu, true);
    w0 = fmaf(sc, va[0], w0); w1 = fmaf(sc, va[1], w1);
    w2 = fmaf(sc, vc[0], w2); w3 = fmaf(sc, vc[1], w3);
    z += sc;
  }
  float inv = 1.f / (8.f * z + 8e-6f);
  ushort4 pk;
  pk.x = f2bf(w0 * inv); pk.y = f2bf(w1 * inv);
  pk.z = f2bf(w2 * inv); pk.w = f2bf(w3 * inv);
  *(ushort4*)(attn + (size_t)node * DIM + l32 * 4) = pk;
}

// ---------------- column-sum stage 1: 128 blocks, NO atomics ----------------
#define CM_BLOCKS 128
__global__ __launch_bounds__(256) void colsum_partial(
    const unsigned short* __restrict__ xb, float* __restrict__ partial)
{
  int cg = threadIdx.x & 15;
  int ro = threadIdx.x >> 4;
  int rows = (N_NODES + CM_BLOCKS - 1) / CM_BLOCKS;
  int r0 = blockIdx.x * rows;
  int r1 = min(r0 + rows, N_NODES);
  float acc[8];
#pragma unroll
  for (int j = 0; j < 8; j++) acc[j] = 0.f;
  int r = r0 + ro;
  for (; r + 48 < r1; r += 64) {
    bf16x8 v0 = *(const bf16x8*)&xb[(size_t)r * 128 + cg * 8];
    bf16x8 v1 = *(const bf16x8*)&xb[(size_t)(r + 16) * 128 + cg * 8];
    bf16x8 v2 = *(const bf16x8*)&xb[(size_t)(r + 32) * 128 + cg * 8];
    bf16x8 v3 = *(const bf16x8*)&xb[(size_t)(r + 48) * 128 + cg * 8];
#pragma unroll
    for (int j = 0; j < 8; j++)
      acc[j] += (bf2f((unsigned short)v0[j]) + bf2f((unsigned short)v1[j])) +
                (bf2f((unsigned short)v2[j]) + bf2f((unsigned short)v3[j]));
  }
  for (; r < r1; r += 16) {
    bf16x8 v = *(const bf16x8*)&xb[(size_t)r * 128 + cg * 8];
#pragma unroll
    for (int j = 0; j < 8; j++) acc[j] += bf2f((unsigned short)v[j]);
  }
  __shared__ float s[16 * 128];
#pragma unroll
  for (int j = 0; j < 8; j++) s[ro * 128 + cg * 8 + j] = acc[j];
  __syncthreads();
#pragma unroll
  for (int step = 8; step >= 1; step >>= 1) {
    if (ro < step) {
#pragma unroll
      for (int j = 0; j < 8; j++)
        s[ro * 128 + cg * 8 + j] += s[(ro + step) * 128 + cg * 8 + j];
    }
    __syncthreads();
  }
  if (ro < 2) {
    int c = ro * 64 + cg * 4;
    *(float4*)&partial[(size_t)blockIdx.x * 128 + c] = *(float4*)&s[c];
  }
}

// ---------------- readout MLP (with partial-reduction prologue) ----------------
__global__ void readout_kernel(
    const float* __restrict__ partial,
    const float* __restrict__ mW0, const float* __restrict__ mb0,
    const float* __restrict__ mW1, const float* __restrict__ mb1,
    const float* __restrict__ mW2, const float* __restrict__ mb2,
    float* __restrict__ out)
{
  __shared__ float sx[128], h0[64], h1[32];
  int t = threadIdx.x;
  {
    float s0 = 0.f, s1 = 0.f, s2 = 0.f, s3 = 0.f;
#pragma unroll 2
    for (int p = 0; p < CM_BLOCKS; p += 4) {
      s0 += partial[(size_t)p * 128 + t];
      s1 += partial[(size_t)(p + 1) * 128 + t];
      s2 += partial[(size_t)(p + 2) * 128 + t];
      s3 += partial[(size_t)(p + 3) * 128 + t];
    }
    sx[t] = ((s0 + s1) + (s2 + s3)) * (1.f / (float)N_NODES);
  }
  __syncthreads();
  if (t < 64) {
    float a = mb0[t];
    for (int i = 0; i < 128; i++) a = fmaf(sx[i], mW0[i * 64 + t], a);
    h0[t] = fmaxf(a, 0.f);
  }
  __syncthreads();
  if (t < 32) {
    float a = mb1[t];
    for (int i = 0; i < 64; i++) a = fmaf(h0[i], mW1[i * 32 + t], a);
    h1[t] = fmaxf(a, 0.f);
  }
  __syncthreads();
  if (t < 10) {
    float a = mb2[t];
    for (int i = 0; i < 32; i++) a = fmaf(h1[i], mW2[i * 10 + t], a);
    out[t] = a;
  }
}

extern "C" void kernel_launch(void* const* d_in, const int* in_sizes, int n_in,
                              void* d_out, int out_size, void* d_ws, size_t ws_size,
                              hipStream_t stream) {
  const int*   x_idx = (const int*)d_in[0];
  const int*   eidx  = (const int*)d_in[1];
  const float* emb   = (const float*)d_in[2];
  const float* Wq = (const float*)d_in[3];  const float* bq = (const float*)d_in[4];
  const float* Wk = (const float*)d_in[5];  const float* bk = (const float*)d_in[6];
  const float* Wv = (const float*)d_in[7];  const float* bv = (const float*)d_in[8];
  const float* Wo = (const float*)d_in[9];  const float* bo = (const float*)d_in[10];
  const float* g1 = (const float*)d_in[11]; const float* be1 = (const float*)d_in[12];
  const float* Wf1 = (const float*)d_in[13]; const float* bf1 = (const float*)d_in[14];
  const float* Wf2 = (const float*)d_in[15]; const float* bf2 = (const float*)d_in[16];
  const float* g2 = (const float*)d_in[17]; const float* be2 = (const float*)d_in[18];
  const float* mW0 = (const float*)d_in[19]; const float* mb0 = (const float*)d_in[20];
  const float* mW1 = (const float*)d_in[21]; const float* mb1 = (const float*)d_in[22];
  const float* mW2 = (const float*)d_in[23]; const float* mb2 = (const float*)d_in[24];
  float* out = (float*)d_out;

  const size_t NX = (size_t)N_NODES * DIM;
  unsigned short* xb  = (unsigned short*)d_ws;
  unsigned short* qkv = xb + NX;
  unsigned short* a   = qkv + (size_t)N_NODES * 256;

  unsigned short* wqkv_p = a + NX;
  unsigned short* wo_p   = wqkv_p + 3 * 128 * 384;
  unsigned short* wf1_p  = wo_p   + 3 * 128 * 128;
  unsigned short* wf2_p  = wf1_p  + 3 * 128 * 256;
  unsigned short* wend   = wf2_p  + 3 * 256 * 128;

  int* counts    = (int*)wend;
  float* partial = (float*)(counts + N_NODES);
  int* offsets   = (int*)(partial + CM_BLOCKS * 128);
  int* bsums     = offsets + N_NODES + 1;
  int* csr       = bsums + 256;
  int* rank      = csr + N_EDGES;

  const int* e0 = eidx;
  const int* e1 = eidx + N_EDGES;

  hipMemsetAsync(counts, 0, N_NODES * sizeof(int), stream);

  prep_all<<<192, 256, 0, stream>>>(Wq, Wk, Wv, Wo, Wf1, Wf2,
                                    wqkv_p, wo_p, wf1_p, wf2_p);

  embed_kernel<<<(N_NODES * 32 + 255) / 256, 256, 0, stream>>>(x_idx, emb, xb);
  hist_kernel<<<(N_EDGES + 255) / 256, 256, 0, stream>>>(e1, counts, rank);
  int nblk = (N_NODES + 255) / 256;
  scan_local<<<nblk, 256, 0, stream>>>(counts, offsets, bsums);
  scan_bsums<<<1, 256, 0, stream>>>(bsums, nblk);
  scan_add<<<nblk, 256, 0, stream>>>(offsets, bsums);
  scatter_kernel<<<(N_EDGES + 255) / 256, 256, 0, stream>>>(e0, e1, offsets, rank, csr);

  int gc = (N_NODES + 63) / 64;
  int nb8 = (N_NODES + 7) / 8;

  qkv0_kernel<<<gc, 256, 0, stream>>>(xb, wqkv_p, bq, bk, bv, qkv, N_NODES);

  for (int l = 0; l < NLAYERS; ++l) {
    const unsigned short* wo_l   = wo_p   + (size_t)l * 128 * 128;
    const unsigned short* wf1_l  = wf1_p  + (size_t)l * 128 * 256;
    const unsigned short* wf2_l  = wf2_p  + (size_t)l * 256 * 128;
    const unsigned short* wqkv_n = wqkv_p + (size_t)(l + 1) * 128 * 384;
    const float* bo_l  = bo  + (size_t)l * DIM;
    const float* g1_l  = g1  + (size_t)l * DIM;
    const float* be1_l = be1 + (size_t)l * DIM;
    const float* bf1_l = bf1 + (size_t)l * 2 * DIM;
    const float* bf2_l = bf2 + (size_t)l * DIM;
    const float* g2_l  = g2  + (size_t)l * DIM;
    const float* be2_l = be2 + (size_t)l * DIM;

    attn_kernel<<<nb8, 256, 0, stream>>>(qkv, offsets, csr, a);
    if (l < NLAYERS - 1) {
      chainM_kernel<false><<<gc, 256, 0, stream>>>(
          a, xb, qkv, wo_l, bo_l, g1_l, be1_l, wf1_l, bf1_l, wf2_l, bf2_l,
          g2_l, be2_l, wqkv_n,
          bq + (size_t)(l + 1) * DIM, bk + (size_t)(l + 1) * DIM,
          bv + (size_t)(l + 1) * DIM, N_NODES);
    } else {
      chainM_kernel<true><<<gc, 256, 0, stream>>>(
          a, xb, qkv, wo_l, bo_l, g1_l, be1_l, wf1_l, bf1_l, wf2_l, bf2_l,
          g2_l, be2_l, wqkv_p, bq, bk, bv, N_NODES);
    }
  }

  colsum_partial<<<CM_BLOCKS, 256, 0, stream>>>(xb, partial);
  readout_kernel<<<1, 128, 0, stream>>>(partial, mW0, mb0, mW1, mb1, mW2, mb2, out);
}